// Round 3
// baseline (409.498 us; speedup 1.0000x reference)
//
#include <hip/hip_runtime.h>

typedef float f32x4 __attribute__((ext_vector_type(4)));
typedef short s16x8 __attribute__((ext_vector_type(8)));

#define MFMA16 __builtin_amdgcn_mfma_f32_16x16x32_bf16

typedef const __attribute__((address_space(1))) void* gptr_t;
typedef __attribute__((address_space(3))) void* lptr_t;

__device__ __forceinline__ unsigned short f2bf(float f) {
    union { float f; unsigned u; } v; v.f = f;
    unsigned r = v.u + 0x7FFF + ((v.u >> 16) & 1);   // RNE
    return (unsigned short)(r >> 16);
}

// ---------------------------------------------------------------------------
// Kernel 0: convert W [1024][64] fp32 -> W_t [192][1024] bf16 (transposed).
// cols 0..63 = Wq (prescaled by 0.125 = H^-0.5), 64..127 = Wk, 128..191 = Wv
// ---------------------------------------------------------------------------
__global__ void prep_w(const float* __restrict__ Wk, const float* __restrict__ Wq,
                       const float* __restrict__ Wv, unsigned short* __restrict__ wt) {
    int n = blockIdx.x;          // 0..191
    int tid = threadIdx.x;       // 0..255
    const float* src; int col; float sc = 1.0f;
    if (n < 64)       { src = Wq; col = n;       sc = 0.125f; }
    else if (n < 128) { src = Wk; col = n - 64; }
    else              { src = Wv; col = n - 128; }
#pragma unroll
    for (int i = 0; i < 4; i++) {
        int c = i * 256 + tid;
        wt[n * 1024 + c] = f2bf(src[c * 64 + col] * sc);
    }
}

// ---------------------------------------------------------------------------
// Fused kernel: one block per batch (grid=256, 512 threads = 8 waves).
// Phase 1: qkv projection, software-pipelined (T3/T4): wt slab [192][64]
//          triple-buffered in LDS (aliases dead Ql+Kl region), slab t+1's
//          11 VMEM ops (3 global_load_lds + 8 float4 x-loads) issued before
//          the barrier, counted s_waitcnt vmcnt(11) (never 0 in-loop).
//          One s_barrier per slab; loads stay in flight across it.
// Phase 2: causal flash attention from LDS. Wave w handles Q-tiles
//          {w, 15-w} (16 rows each) for balanced causal work.
// ---------------------------------------------------------------------------
__global__ __launch_bounds__(512, 2) void fused_kernel(const float* __restrict__ x,
                                                       const unsigned short* __restrict__ wt,
                                                       float* __restrict__ out) {
    // carved shared block: Ql[256*72] | Kl[256*72] | Vt[64*264] | Pl[8][16*56]
    // Wl triple-buffer (3 x 12288 shorts = 72KB) aliases Ql+Kl (proj phase only).
    __shared__ unsigned short smem[2 * 256 * 72 + 64 * 264 + 8 * 16 * 56];
    unsigned short* Ql  = smem;
    unsigned short* Kl  = smem + 256 * 72;
    unsigned short* Vt  = smem + 2 * 256 * 72;
    unsigned short* Pl8 = smem + 2 * 256 * 72 + 64 * 264;
    unsigned short* const Wb0 = smem;
    unsigned short* const Wb1 = smem + 12288;
    unsigned short* const Wb2 = smem + 24576;
    unsigned short* const Wb[3] = { Wb0, Wb1, Wb2 };

    const int tid  = threadIdx.x;
    const int lane = tid & 63;
    const int wid  = tid >> 6;       // 0..7
    const int quad = lane >> 4;
    const int l15  = lane & 15;
    const int b    = blockIdx.x;
    const int m0   = wid * 32;

    const float* xb  = x + (long)b * 256 * 1024;
    const float* ar0 = xb + (long)(m0 + l15) * 1024 + quad * 8;
    const float* ar1 = ar0 + 16 * 1024;

    // wt staging: wave w stages rows [24w, 24w+24), 3 global_load_lds of 1KB.
    const int srow = wid * 24 + (lane >> 3);   // slot row for j=0
    const int cswz = (lane & 7) ^ (lane >> 3); // pre-swizzled source chunk (j-invariant)

    // ds_read swizzle offsets (rr&7 == l15&7 for all nt)
    const int woff0 = l15 * 64 + ((0 + quad) ^ (l15 & 7)) * 8;  // kk=0
    const int woff1 = l15 * 64 + ((4 + quad) ^ (l15 & 7)) * 8;  // kk=32

    // ======== phase 1: QKV projection (pipelined) ========
    f32x4 acc[2][12] = {};
    float4 px[2][8];

    auto issueStage = [&](int t, unsigned short* Wd) {
        const unsigned short* s0 = wt + (long)srow * 1024 + t * 64 + cswz * 8;
#pragma unroll
        for (int j = 0; j < 3; j++)
            __builtin_amdgcn_global_load_lds((gptr_t)(s0 + j * 8 * 1024),
                                             (lptr_t)(Wd + (wid * 24 + j * 8) * 64), 16, 0, 0);
    };
    auto issueX = [&](int t, float4* p) {
        const int k0 = t * 64;
        p[0] = *(const float4*)(ar0 + k0);      p[1] = *(const float4*)(ar0 + k0 + 4);
        p[2] = *(const float4*)(ar0 + k0 + 32); p[3] = *(const float4*)(ar0 + k0 + 36);
        p[4] = *(const float4*)(ar1 + k0);      p[5] = *(const float4*)(ar1 + k0 + 4);
        p[6] = *(const float4*)(ar1 + k0 + 32); p[7] = *(const float4*)(ar1 + k0 + 36);
    };

    issueStage(0, Wb0);
    issueX(0, px[0]);

#pragma unroll
    for (int t = 0; t < 16; t++) {
        if (t < 15) {
            issueStage(t + 1, Wb[(t + 1) % 3]);
            issueX(t + 1, px[(t + 1) & 1]);
        }
        __builtin_amdgcn_sched_barrier(0);
        if (t < 15) asm volatile("s_waitcnt vmcnt(11)" ::: "memory");
        else        asm volatile("s_waitcnt vmcnt(0)"  ::: "memory");
        __builtin_amdgcn_s_barrier();
        __builtin_amdgcn_sched_barrier(0);

        const unsigned short* Wd = Wb[t % 3];
        float4* p = px[t & 1];
#pragma unroll
        for (int kk = 0; kk < 2; kk++) {
            const unsigned short* wbp = Wd + (kk ? woff1 : woff0);
            s16x8 bfv[12];
#pragma unroll
            for (int nt = 0; nt < 12; nt++)
                bfv[nt] = *(const s16x8*)(wbp + nt * 1024);

            const float4 a0 = p[kk * 2 + 0], a1 = p[kk * 2 + 1];
            const float4 a2 = p[kk * 2 + 4], a3 = p[kk * 2 + 5];
            s16x8 af0 = { (short)f2bf(a0.x), (short)f2bf(a0.y), (short)f2bf(a0.z), (short)f2bf(a0.w),
                          (short)f2bf(a1.x), (short)f2bf(a1.y), (short)f2bf(a1.z), (short)f2bf(a1.w) };
            s16x8 af1 = { (short)f2bf(a2.x), (short)f2bf(a2.y), (short)f2bf(a2.z), (short)f2bf(a2.w),
                          (short)f2bf(a3.x), (short)f2bf(a3.y), (short)f2bf(a3.z), (short)f2bf(a3.w) };
#pragma unroll
            for (int nt = 0; nt < 12; nt++) {
                acc[0][nt] = MFMA16(af0, bfv[nt], acc[0][nt], 0, 0, 0);
                acc[1][nt] = MFMA16(af1, bfv[nt], acc[1][nt], 0, 0, 0);
            }
        }
    }
    __syncthreads();   // Wl dead; safe to overwrite Ql/Kl in epilogue

    // ---- epilogue: Q,K row-major; V transposed (acc regs hold 4 consecutive rows) ----
#pragma unroll
    for (int mt = 0; mt < 2; mt++) {
#pragma unroll
        for (int nt = 0; nt < 12; nt++) {
            if (nt < 4) {
#pragma unroll
                for (int r = 0; r < 4; r++)
                    Ql[(m0 + mt * 16 + quad * 4 + r) * 72 + nt * 16 + l15] = f2bf(acc[mt][nt][r]);
            } else if (nt < 8) {
#pragma unroll
                for (int r = 0; r < 4; r++)
                    Kl[(m0 + mt * 16 + quad * 4 + r) * 72 + (nt - 4) * 16 + l15] = f2bf(acc[mt][nt][r]);
            } else {
                ushort4 pv;
                pv.x = f2bf(acc[mt][nt][0]); pv.y = f2bf(acc[mt][nt][1]);
                pv.z = f2bf(acc[mt][nt][2]); pv.w = f2bf(acc[mt][nt][3]);
                *(ushort4*)&Vt[((nt - 8) * 16 + l15) * 264 + m0 + mt * 16 + quad * 4] = pv;
            }
        }
    }
    __syncthreads();

    // ======== phase 2: causal attention ========
    unsigned short* Pw = Pl8 + wid * (16 * 56);

#pragma unroll
    for (int ti = 0; ti < 2; ti++) {
        const int r0 = (ti == 0 ? wid : 15 - wid) * 16;   // balanced tile pair

        s16x8 qf0 = *(const s16x8*)&Ql[(r0 + l15) * 72 + quad * 8];
        s16x8 qf1 = *(const s16x8*)&Ql[(r0 + l15) * 72 + 32 + quad * 8];

        f32x4 o[4] = {};
        float mr[4], lr[4];
#pragma unroll
        for (int r = 0; r < 4; r++) { mr[r] = -1e30f; lr[r] = 0.0f; }

        const int nst = (r0 >> 5) + 1;
        for (int st = 0; st < nst; st++) {
            const int s0 = st * 32;
            s16x8 kf00 = *(const s16x8*)&Kl[(s0 + l15) * 72 + quad * 8];
            s16x8 kf01 = *(const s16x8*)&Kl[(s0 + l15) * 72 + 32 + quad * 8];
            s16x8 kf10 = *(const s16x8*)&Kl[(s0 + 16 + l15) * 72 + quad * 8];
            s16x8 kf11 = *(const s16x8*)&Kl[(s0 + 16 + l15) * 72 + 32 + quad * 8];
            s16x8 vf[4];
#pragma unroll
            for (int n = 0; n < 4; n++)
                vf[n] = *(const s16x8*)&Vt[(n * 16 + l15) * 264 + s0 + quad * 8];

            f32x4 S0 = {0.f, 0.f, 0.f, 0.f}, S1 = {0.f, 0.f, 0.f, 0.f};
            S0 = MFMA16(qf0, kf00, S0, 0, 0, 0);
            S0 = MFMA16(qf1, kf01, S0, 0, 0, 0);
            S1 = MFMA16(qf0, kf10, S1, 0, 0, 0);
            S1 = MFMA16(qf1, kf11, S1, 0, 0, 0);

            if (s0 + 31 > r0) {   // diagonal tile: causal mask
#pragma unroll
                for (int r = 0; r < 4; r++) {
                    int t = r0 + quad * 4 + r;
                    if (s0 + l15 > t)      S0[r] = -1e30f;
                    if (s0 + 16 + l15 > t) S1[r] = -1e30f;
                }
            }

            float a4[4];
#pragma unroll
            for (int r = 0; r < 4; r++) {
                float rm = fmaxf(S0[r], S1[r]);
                rm = fmaxf(rm, __shfl_xor(rm, 1));
                rm = fmaxf(rm, __shfl_xor(rm, 2));
                rm = fmaxf(rm, __shfl_xor(rm, 4));
                rm = fmaxf(rm, __shfl_xor(rm, 8));
                float mn = fmaxf(mr[r], rm);
                float al = exp2f((mr[r] - mn) * 1.44269504f);
                mr[r] = mn;
                float p0 = exp2f((S0[r] - mn) * 1.44269504f);
                float p1 = exp2f((S1[r] - mn) * 1.44269504f);
                float rs = p0 + p1;
                rs += __shfl_xor(rs, 1);
                rs += __shfl_xor(rs, 2);
                rs += __shfl_xor(rs, 4);
                rs += __shfl_xor(rs, 8);
                lr[r] = al * lr[r] + rs;
                a4[r] = al;
                Pw[(quad * 4 + r) * 56 + l15]      = f2bf(p0);
                Pw[(quad * 4 + r) * 56 + l15 + 16] = f2bf(p1);
            }
#pragma unroll
            for (int n = 0; n < 4; n++) {
                f32x4 tt = o[n];
#pragma unroll
                for (int r = 0; r < 4; r++) tt[r] *= a4[r];
                o[n] = tt;
            }
            s16x8 pf = *(const s16x8*)&Pw[l15 * 56 + quad * 8];
#pragma unroll
            for (int n = 0; n < 4; n++)
                o[n] = MFMA16(pf, vf[n], o[n], 0, 0, 0);
        }

        // ---- normalize + store ----
        float inv[4];
#pragma unroll
        for (int r = 0; r < 4; r++) inv[r] = 1.0f / lr[r];
#pragma unroll
        for (int n = 0; n < 4; n++)
#pragma unroll
            for (int r = 0; r < 4; r++) {
                long t = (long)b * 256 + r0 + quad * 4 + r;
                out[t * 64 + n * 16 + l15] = o[n][r] * inv[r];
            }
    }
}

// ---------------------------------------------------------------------------
extern "C" void kernel_launch(void* const* d_in, const int* in_sizes, int n_in,
                              void* d_out, int out_size, void* d_ws, size_t ws_size,
                              hipStream_t stream) {
    const float* x  = (const float*)d_in[0];
    const float* Wk = (const float*)d_in[1];
    const float* Wq = (const float*)d_in[2];
    const float* Wv = (const float*)d_in[3];
    float* out = (float*)d_out;

    unsigned short* wt = (unsigned short*)d_ws;   // 192*1024 bf16

    prep_w<<<192, 256, 0, stream>>>(Wk, Wq, Wv, wt);
    fused_kernel<<<256, 512, 0, stream>>>(x, wt, out);
}